// Round 14
// baseline (774.321 us; speedup 1.0000x reference)
//
#include <hip/hip_runtime.h>
#include <hip/hip_bf16.h>

// Problem: out[M=4096][N=16384] = x[M][K=4096] @ (W[N][K] * scale[N/128][K/128])^T + bias[N]
#define M_DIM 4096
#define N_DIM 16384
#define K_DIM 4096

typedef __bf16 bf16x8 __attribute__((ext_vector_type(8)));
typedef float f32x4 __attribute__((ext_vector_type(4)));

__device__ __forceinline__ void gload16(const void* g, void* l) {
    __builtin_amdgcn_global_load_lds((__attribute__((address_space(1))) void*)g,
                                     (__attribute__((address_space(3))) void*)l, 16, 0, 0);
}

// ---------- prepass 1: x fp32 -> bf16 ----------
__global__ __launch_bounds__(256) void cvt_x_kernel(const float* __restrict__ x,
                                                    __hip_bfloat16* __restrict__ out,
                                                    int ngroups) {
    int i = blockIdx.x * blockDim.x + threadIdx.x;
    int stride = gridDim.x * blockDim.x;
    for (; i < ngroups; i += stride) {
        const float4* p = (const float4*)(x + (size_t)i * 8);
        float4 v0 = p[0];
        float4 v1 = p[1];
        bf16x8 r;
        r[0] = (__bf16)v0.x; r[1] = (__bf16)v0.y; r[2] = (__bf16)v0.z; r[3] = (__bf16)v0.w;
        r[4] = (__bf16)v1.x; r[5] = (__bf16)v1.y; r[6] = (__bf16)v1.z; r[7] = (__bf16)v1.w;
        *(bf16x8*)(out + (size_t)i * 8) = r;
    }
}

// ---------- prepass 2: W fp32 * blockscale -> bf16 ----------
__global__ __launch_bounds__(256) void dequant_w_kernel(const float* __restrict__ w,
                                                        const float* __restrict__ scale,
                                                        __hip_bfloat16* __restrict__ out) {
    const int ngroups = N_DIM * (K_DIM / 8);
    int i = blockIdx.x * blockDim.x + threadIdx.x;
    int stride = gridDim.x * blockDim.x;
    for (; i < ngroups; i += stride) {
        int row = i >> 9;
        int cg  = i & 511;
        float s = scale[(row >> 7) * (K_DIM / 128) + (cg >> 4)];
        const float4* p = (const float4*)(w + (size_t)i * 8);
        float4 v0 = p[0];
        float4 v1 = p[1];
        bf16x8 r;
        r[0] = (__bf16)(v0.x * s); r[1] = (__bf16)(v0.y * s);
        r[2] = (__bf16)(v0.z * s); r[3] = (__bf16)(v0.w * s);
        r[4] = (__bf16)(v1.x * s); r[5] = (__bf16)(v1.y * s);
        r[6] = (__bf16)(v1.z * s); r[7] = (__bf16)(v1.w * s);
        *(bf16x8*)(out + (size_t)i * 8) = r;
    }
}

// ---------- main GEMM: 256x256, BK=64, 8 waves, 8-phase + READ-AHEAD ---------
// Single change vs r9/r13: every ds_read group issues ONE PHASE EARLY with a
// counted lgkm wait, so each phase's LDS burst completes under the previous
// phase's MFMA issue (pipes overlap; r5-r13 were issue-order serial).
// Per-phase (steady): {issue reads for NEXT phase; stage (r9 slots);
// WAITL(n) for THIS phase's reads; BAR; MFMA; BAR}.
//   P1: iss b23   WAITL(4)   MM(a03,b01)     P5: mirror on buf1
//   P2: iss a47   WAITL(8)   MM(a03,b23)     P6: mirror
//   P3: iss --    WAITL(0)   MM(a47,b01)     P7: mirror
//   P4: SH+vmcnt(4)+BAR; iss {a03,b01}(buf1); MM(a47,b23)   P8: mirror(buf0)
// The 12-read group issues at P4/P8 AFTER vmcnt(4)+BAR — r9's invariant
// proves the buffer fully resident there (P4 retires P7',P8',P1,P2 = buf1;
// P8 retires P3..P6 = buf0-next). Counted waits are exact (in-order DS
// retire): P1 outstanding=12(prev P8)+4 -> WAITL(4) retires the 12; P2
// outstanding<=4+8 -> WAITL(8) retires b23; P3 WAITL(0) drains a47 (1 phase
// slack). Frag lifetimes interleave -> all single-buffered (no VGPR growth).
// Stage slots / vmcnt / barriers byte-identical to r9 (race-proven 5 runs).
__global__ __launch_bounds__(512, 2)
void gemm_bf16_kernel(const __hip_bfloat16* __restrict__ A,   // [M][K] bf16
                      const __hip_bfloat16* __restrict__ Bw,  // [N][K] bf16
                      const float* __restrict__ bias,
                      float* __restrict__ C) {                // [M][N] fp32
    constexpr int Mtiles = M_DIM / 256;            // 16
    constexpr int Ntiles = N_DIM / 256;            // 64
    constexpr int nwg = Mtiles * Ntiles;           // 1024 (div by 8)

    int bid = blockIdx.x;
    int swz = (bid & 7) * (nwg >> 3) + (bid >> 3);   // bijective XCD swizzle
    int bm = swz % Mtiles;
    int bn = swz / Mtiles;

    __shared__ bf16x8 sA[2][2048];   // 256 rows x 8 slots x 16B = 32 KiB each
    __shared__ bf16x8 sB[2][2048];   // total 128 KiB

    const int t = threadIdx.x;
    const int l = t & 63;
    const int w = t >> 6;        // wave 0..7
    const int wm = w >> 2;       // 0..1  (M half)
    const int wn = w & 3;        // 0..3  (N quarter)

    const int lr = l & 15;
    const int lk = l >> 4;
    const int l7 = lr & 7;

    // read slots: logical slot (s*4+lk) of row with row&7==l7 (XOR swizzle)
    const int s0 = lk ^ l7;            // k-half 0
    const int s1 = (4 + lk) ^ l7;      // k-half 1

    // staging (rule #21): linear LDS dest, pre-swizzled global source col.
    const int srow = w * 8 + (l >> 3);
    const int scol = ((l & 7) ^ (l >> 3)) << 3;

    const size_t K = K_DIM;
    const __hip_bfloat16* aB = A  + (size_t)(bm * 256) * K + scol;
    const __hip_bfloat16* bB = Bw + (size_t)(bn * 256) * K + scol;

    f32x4 acc[8][4] = {};

    const int arow = (wm * 128 + lr) * 8;   // slot base of A fragment rows
    const int brow = (wn * 64 + lr) * 8;    // slot base of B fragment rows

    char* A0b = (char*)&sA[0][0] + w * 1024;   // stage dest (+half*16384)
    char* B0b = (char*)&sB[0][0] + w * 1024;
    char* A1b = (char*)&sA[1][0] + w * 1024;
    char* B1b = (char*)&sB[1][0] + w * 1024;

// stage one half-tile (128 rows x 64 cols): 2 gloads/thread
#define SH(lbase, gptr)                                                         \
    do {                                                                        \
        gload16((gptr) + (size_t)srow * K, (lbase));                            \
        gload16((gptr) + (size_t)(64 + srow) * K, (lbase) + 8192);              \
    } while (0)

#define RD_A03(pa_)                                                             \
    { _Pragma("unroll")                                                         \
      for (int mi = 0; mi < 4; ++mi) {                                          \
          a03[mi][0] = (pa_)[arow + mi * 128 + s0];                             \
          a03[mi][1] = (pa_)[arow + mi * 128 + s1];                             \
      } }

#define RD_A47(pa_)                                                             \
    { _Pragma("unroll")                                                         \
      for (int mi = 0; mi < 4; ++mi) {                                          \
          a47[mi][0] = (pa_)[arow + 512 + mi * 128 + s0];                       \
          a47[mi][1] = (pa_)[arow + 512 + mi * 128 + s1];                       \
      } }

#define RD_B01(pb_)                                                             \
    { _Pragma("unroll")                                                         \
      for (int ni = 0; ni < 2; ++ni) {                                          \
          b01[ni][0] = (pb_)[brow + ni * 128 + s0];                             \
          b01[ni][1] = (pb_)[brow + ni * 128 + s1];                             \
      } }

#define RD_B23(pb_)                                                             \
    { _Pragma("unroll")                                                         \
      for (int ni = 0; ni < 2; ++ni) {                                          \
          b23[ni][0] = (pb_)[brow + 256 + ni * 128 + s0];                       \
          b23[ni][1] = (pb_)[brow + 256 + ni * 128 + s1];                       \
      } }

#define MM(mo, no, af, bf)                                                      \
    do {                                                                        \
        __builtin_amdgcn_s_setprio(1);                                          \
        _Pragma("unroll")                                                       \
        for (int s = 0; s < 2; ++s)                                             \
            _Pragma("unroll")                                                   \
            for (int mi = 0; mi < 4; ++mi)                                      \
                _Pragma("unroll")                                               \
                for (int ni = 0; ni < 2; ++ni)                                  \
                    acc[(mo) + mi][(no) + ni] =                                 \
                        __builtin_amdgcn_mfma_f32_16x16x32_bf16(                \
                            af[mi][s], bf[ni][s], acc[(mo) + mi][(no) + ni],    \
                            0, 0, 0);                                           \
        __builtin_amdgcn_s_setprio(0);                                          \
    } while (0)

#define BAR()   __builtin_amdgcn_s_barrier()
#define SBAR()  __builtin_amdgcn_sched_barrier(0)
#define WAITL(n) do { asm volatile("s_waitcnt lgkmcnt(" #n ")" ::: "memory"); SBAR(); } while (0)

    bf16x8 a03[4][2], a47[4][2], b01[2][2], b23[2][2];
    const bf16x8* pa0 = &sA[0][0];
    const bf16x8* pb0 = &sB[0][0];
    const bf16x8* pa1 = &sA[1][0];
    const bf16x8* pb1 = &sB[1][0];

    // prologue: tile0 full -> buf0; tile1 B halves -> buf1.B ; keep newest 4
    SH(A0b, aB);  SH(A0b + 16384, aB + (size_t)128 * K);
    SH(B0b, bB);  SH(B0b + 16384, bB + (size_t)128 * K);
    SH(B1b, bB + 64);  SH(B1b + 16384, bB + 64 + (size_t)128 * K);
    asm volatile("s_waitcnt vmcnt(4)" ::: "memory");   // tile0 resident
    BAR();
    RD_A03(pa0); RD_B01(pb0);     // pre-issue P1's data (waited at P1)
    SBAR();

    #pragma unroll 1
    for (int p = 0; p < 32; ++p) {
        const bool last = (p == 31);
        const __hip_bfloat16* gAu  = aB + (size_t)(2 * p + 1) * 64;
        const __hip_bfloat16* gAt2 = aB + (size_t)(2 * p + 2) * 64;
        const __hip_bfloat16* gBt2 = bB + (size_t)(2 * p + 2) * 64;
        const __hip_bfloat16* gBt3 = bB + (size_t)(2 * p + 3) * 64;

        // ================= K-tile t = 2p (buf0) =================
        // --- P1: iss b23(P2); stage buf1.A0<-u; WAITL(4); MM(a03,b01) ---
        RD_B23(pb0);
        SH(A1b, gAu);
        WAITL(4);
        BAR();
        SBAR();
        MM(0, 0, a03, b01);
        BAR();
        // --- P2: iss a47(P3); stage buf1.A1<-u; WAITL(8); MM(a03,b23) ---
        RD_A47(pa0);
        SH(A1b + 16384, gAu + (size_t)128 * K);
        WAITL(8);
        BAR();
        SBAR();
        MM(0, 2, a03, b23);
        BAR();
        // --- P3: stage buf0.B0<-t2; WAITL(0) [a47, 1-phase slack]; MM ---
        if (!last) SH(B0b, gBt2);
        WAITL(0);
        BAR();
        SBAR();
        MM(4, 0, a47, b01);
        BAR();
        // --- P4: stage buf0.B1<-t2; vmcnt(4); BAR; iss {a03,b01}(buf1); MM ---
        if (!last) {
            SH(B0b + 16384, gBt2 + (size_t)128 * K);
            asm volatile("s_waitcnt vmcnt(4)" ::: "memory");
        } else {
            asm volatile("s_waitcnt vmcnt(0)" ::: "memory");
        }
        BAR();
        RD_A03(pa1); RD_B01(pb1);      // buf1 resident (vmcnt retired its 8)
        SBAR();
        MM(4, 2, a47, b23);            // operands waited at P2/P3
        BAR();

        // ================= K-tile u = 2p+1 (buf1) =================
        // --- P5: iss b23(P6); stage buf0.A0<-t2; WAITL(4); MM(a03,b01) ---
        RD_B23(pb1);
        if (!last) SH(A0b, gAt2);
        WAITL(4);
        BAR();
        SBAR();
        MM(0, 0, a03, b01);
        BAR();
        // --- P6: iss a47(P7); stage buf0.A1<-t2; WAITL(8); MM(a03,b23) ---
        RD_A47(pa1);
        if (!last) SH(A0b + 16384, gAt2 + (size_t)128 * K);
        WAITL(8);
        BAR();
        SBAR();
        MM(0, 2, a03, b23);
        BAR();
        // --- P7: stage buf1.B0<-t3; WAITL(0); MM(a47,b01) ---
        if (!last) SH(B1b, gBt3);
        WAITL(0);
        BAR();
        SBAR();
        MM(4, 0, a47, b01);
        BAR();
        // --- P8: stage buf1.B1<-t3; vmcnt(4); BAR; iss {a03,b01}(buf0'); MM ---
        if (!last) {
            SH(B1b + 16384, gBt3 + (size_t)128 * K);
            asm volatile("s_waitcnt vmcnt(4)" ::: "memory");
        }
        BAR();
        if (!last) {
            RD_A03(pa0); RD_B01(pb0);  // buf0 (t+2) resident (vmcnt retired P3..P6)
        }
        SBAR();
        MM(4, 2, a47, b23);
        if (!last) BAR();
    }
#undef SH
#undef RD_A03
#undef RD_A47
#undef RD_B01
#undef RD_B23
#undef MM
#undef BAR
#undef SBAR
#undef WAITL

    // epilogue: C/D layout col=lane&15, row=(lane>>4)*4+reg  [m89-verified]
    const int crow0 = bm * 256 + wm * 128;
    const int ccol0 = bn * 256 + wn * 64;
    #pragma unroll
    for (int ni = 0; ni < 4; ++ni) {
        int col = ccol0 + ni * 16 + lr;
        float bv = bias[col];
        #pragma unroll
        for (int mi = 0; mi < 8; ++mi) {
            int rbase = crow0 + mi * 16 + lk * 4;
            #pragma unroll
            for (int j = 0; j < 4; ++j) {
                C[(size_t)(rbase + j) * N_DIM + col] = acc[mi][ni][j] + bv;
            }
        }
    }
}

// ---------- fallback (ws too small): fp32 LDS-tiled, correct but slow ----------
__global__ __launch_bounds__(256)
void gemm_fallback(const float* __restrict__ X, const float* __restrict__ W,
                   const float* __restrict__ scale, const float* __restrict__ bias,
                   float* __restrict__ C) {
    int bm = blockIdx.x % (M_DIM / 64);
    int bn = blockIdx.x / (M_DIM / 64);
    __shared__ float sA[64][33];
    __shared__ float sB[64][33];
    int t = threadIdx.x;
    int tx = t & 15, ty = t >> 4;
    float acc[4][4] = {};
    for (int kt = 0; kt < K_DIM / 32; ++kt) {
        float s = scale[(bn >> 1) * (K_DIM / 128) + (kt >> 2)];
        #pragma unroll
        for (int i = 0; i < 8; ++i) {
            int idx = t + i * 256;
            int r = idx >> 5, c = idx & 31;
            sA[r][c] = X[(size_t)(bm * 64 + r) * K_DIM + kt * 32 + c];
            sB[r][c] = W[(size_t)(bn * 64 + r) * K_DIM + kt * 32 + c] * s;
        }
        __syncthreads();
        #pragma unroll
        for (int k = 0; k < 32; ++k) {
            float a[4], b[4];
            #pragma unroll
            for (int i = 0; i < 4; ++i) a[i] = sA[ty * 4 + i][k];
            #pragma unroll
            for (int j = 0; j < 4; ++j) b[j] = sB[tx * 4 + j][k];
            #pragma unroll
            for (int i = 0; i < 4; ++i)
                #pragma unroll
                for (int j = 0; j < 4; ++j) acc[i][j] += a[i] * b[j];
        }
        __syncthreads();
    }
    #pragma unroll
    for (int i = 0; i < 4; ++i)
        #pragma unroll
        for (int j = 0; j < 4; ++j) {
            int row = bm * 64 + ty * 4 + i;
            int col = bn * 64 + tx * 4 + j;
            C[(size_t)row * N_DIM + col] = acc[i][j] + bias[col];
        }
}

extern "C" void kernel_launch(void* const* d_in, const int* in_sizes, int n_in,
                              void* d_out, int out_size, void* d_ws, size_t ws_size,
                              hipStream_t stream) {
    const float* x     = (const float*)d_in[0];   // [2,2048,4096]
    const float* wgt   = (const float*)d_in[1];   // [16384,4096]
    const float* scale = (const float*)d_in[2];   // [128,32]
    const float* bias  = (const float*)d_in[3];   // [16384]
    float* out = (float*)d_out;                   // [2,2048,16384]

    const size_t need = ((size_t)M_DIM * K_DIM + (size_t)N_DIM * K_DIM) * sizeof(__hip_bfloat16);
    if (ws_size >= need) {
        __hip_bfloat16* xbf = (__hip_bfloat16*)d_ws;
        __hip_bfloat16* wbf = xbf + (size_t)M_DIM * K_DIM;
        cvt_x_kernel<<<2048, 256, 0, stream>>>(x, xbf, M_DIM * K_DIM / 8);
        dequant_w_kernel<<<4096, 256, 0, stream>>>(wgt, scale, wbf);
        gemm_bf16_kernel<<<(M_DIM / 256) * (N_DIM / 256), 512, 0, stream>>>(xbf, wbf, bias, out);
    } else {
        gemm_fallback<<<(M_DIM / 64) * (N_DIM / 64), 256, 0, stream>>>(x, wgt, scale, bias, out);
    }
}

// Round 15
// 702.423 us; speedup vs baseline: 1.1024x; 1.1024x over previous
//
#include <hip/hip_runtime.h>
#include <hip/hip_bf16.h>

// Problem: out[M=4096][N=16384] = x[M][K=4096] @ (W[N][K] * scale[N/128][K/128])^T + bias[N]
#define M_DIM 4096
#define N_DIM 16384
#define K_DIM 4096

typedef __bf16 bf16x8 __attribute__((ext_vector_type(8)));
typedef float f32x16 __attribute__((ext_vector_type(16)));

__device__ __forceinline__ void gload16(const void* g, void* l) {
    __builtin_amdgcn_global_load_lds((__attribute__((address_space(1))) void*)g,
                                     (__attribute__((address_space(3))) void*)l, 16, 0, 0);
}

// ---------- fused prepass: x fp32->bf16  +  W fp32*scale->bf16 ----------
__global__ __launch_bounds__(256) void prep_kernel(const float* __restrict__ x,
                                                   const float* __restrict__ wgt,
                                                   const float* __restrict__ scale,
                                                   __hip_bfloat16* __restrict__ xbf,
                                                   __hip_bfloat16* __restrict__ wbf) {
    int b = blockIdx.x;
    if (b < 2048) {
        const int ng = M_DIM * K_DIM / 8;
        int i = b * 256 + threadIdx.x;
        for (; i < ng; i += 2048 * 256) {
            const float4* p = (const float4*)(x + (size_t)i * 8);
            float4 v0 = p[0];
            float4 v1 = p[1];
            bf16x8 r;
            r[0] = (__bf16)v0.x; r[1] = (__bf16)v0.y; r[2] = (__bf16)v0.z; r[3] = (__bf16)v0.w;
            r[4] = (__bf16)v1.x; r[5] = (__bf16)v1.y; r[6] = (__bf16)v1.z; r[7] = (__bf16)v1.w;
            *(bf16x8*)(xbf + (size_t)i * 8) = r;
        }
    } else {
        const int ng = N_DIM * (K_DIM / 8);
        int i = (b - 2048) * 256 + threadIdx.x;
        for (; i < ng; i += 4096 * 256) {
            int row = i >> 9;
            int cg  = i & 511;
            float s = scale[(row >> 7) * (K_DIM / 128) + (cg >> 4)];
            const float4* p = (const float4*)(wgt + (size_t)i * 8);
            float4 v0 = p[0];
            float4 v1 = p[1];
            bf16x8 r;
            r[0] = (__bf16)(v0.x * s); r[1] = (__bf16)(v0.y * s);
            r[2] = (__bf16)(v0.z * s); r[3] = (__bf16)(v0.w * s);
            r[4] = (__bf16)(v1.x * s); r[5] = (__bf16)(v1.y * s);
            r[6] = (__bf16)(v1.z * s); r[7] = (__bf16)(v1.w * s);
            *(bf16x8*)(wbf + (size_t)i * 8) = r;
        }
    }
}

// ---------- main GEMM: 256x256, BK=64, 8 waves, r13 8-phase + 32x32x16 MFMA --
// Single functional change vs r13 (best, 631us): MFMA shape 16x16x32 ->
// 32x32x16 (m119: 2495 vs 2176 TF ceiling; per-K-tile MFMA pipe 2483->2066
// cyc; half the MFMA instruction count). Same LDS bytes. Layouts:
//   A: lane l -> row l&31, k = 8*(l>>5)+j  (32-wide mirror of verified 16x16)
//   B: lane l -> col l&31, same k          (symmetric)
//   C/D: col = lane&31, row = (reg&3)+8*(reg>>2)+4*(lane>>5)  [m74/m101]
// Swizzle for the 32-row read pattern: sigma(r) = (r&7)^((r>>3)&3);
// stored phys slot = logical ^ sigma(row). Read slot (kc,lh) =
// (kc*2+lh)^(l&7)^((l>>3)&3). Stage side (rule #21): linear LDS dest,
// pre-swizzled global col g = (l&7)^(l>>3)^(w&3) — offset-invariant across
// +64/+128-row half-tiles (checked: (r>>3)&3 == w&3 for all three).
// Schedule/stages/vmcnt/barriers byte-identical to r13.
__global__ __launch_bounds__(512, 2)
void gemm_bf16_kernel(const __hip_bfloat16* __restrict__ A,   // [M][K] bf16
                      const __hip_bfloat16* __restrict__ Bw,  // [N][K] bf16
                      const float* __restrict__ bias,
                      float* __restrict__ C) {                // [M][N] fp32
    constexpr int Mtiles = M_DIM / 256;            // 16
    constexpr int Ntiles = N_DIM / 256;            // 64
    constexpr int nwg = Mtiles * Ntiles;           // 1024 (div by 8)

    int bid = blockIdx.x;
    int swz = (bid & 7) * (nwg >> 3) + (bid >> 3);   // bijective XCD swizzle
    int bm = swz % Mtiles;
    int bn = swz / Mtiles;

    __shared__ bf16x8 sA[2][2048];   // 256 rows x 8 slots x 16B = 32 KiB each
    __shared__ bf16x8 sB[2][2048];   // total 128 KiB

    const int t = threadIdx.x;
    const int l = t & 63;
    const int w = t >> 6;        // wave 0..7
    const int wm = w >> 2;       // 0..1  (M half)
    const int wn = w & 3;        // 0..3  (N quarter)

    const int l31 = l & 31;
    const int lh  = l >> 5;                       // k-half within chunk
    const int sig = (l & 7) ^ ((l >> 3) & 3);     // sigma(base+l31), base%32==0

    // read slots for k-chunk kc (K=16 each): logical (kc*2+lh) ^ sigma
    const int sk[4] = { (0 + lh) ^ sig, (2 + lh) ^ sig,
                        (4 + lh) ^ sig, (6 + lh) ^ sig };

    // staging (rule #21): linear LDS dest, pre-swizzled global source col.
    const int srow = w * 8 + (l >> 3);
    const int scol = ((l & 7) ^ (l >> 3) ^ (w & 3)) << 3;

    const size_t K = K_DIM;
    const __hip_bfloat16* aB = A  + (size_t)(bm * 256) * K + scol;
    const __hip_bfloat16* bB = Bw + (size_t)(bn * 256) * K + scol;

    f32x16 acc[4][2] = {};   // [sm 32-row subtile][sn 32-col subtile]

    const int arow = (wm * 128 + l31) * 8;   // slot base of A fragment rows
    const int brow = (wn * 64 + l31) * 8;    // slot base of B fragment rows

    char* A0b = (char*)&sA[0][0] + w * 1024;   // stage dest (+half*16384)
    char* B0b = (char*)&sB[0][0] + w * 1024;
    char* A1b = (char*)&sA[1][0] + w * 1024;
    char* B1b = (char*)&sB[1][0] + w * 1024;

// stage one half-tile (128 rows x 64 cols): 2 gloads/thread
#define SH(lbase, gptr)                                                         \
    do {                                                                        \
        gload16((gptr) + (size_t)srow * K, (lbase));                            \
        gload16((gptr) + (size_t)(64 + srow) * K, (lbase) + 8192);              \
    } while (0)

// A: 2 subtiles x 4 k-chunks (8 reads); B: 4 k-chunks (4 reads)
#define RD_A(dst, pa_, roff)                                                    \
    _Pragma("unroll")                                                           \
    for (int sm = 0; sm < 2; ++sm)                                              \
        _Pragma("unroll")                                                       \
        for (int kc = 0; kc < 4; ++kc)                                          \
            dst[sm][kc] = (pa_)[arow + (roff) + sm * 256 + sk[kc]];

#define RD_B(dst, pb_, roff)                                                    \
    _Pragma("unroll")                                                           \
    for (int kc = 0; kc < 4; ++kc)                                              \
        dst[kc] = (pb_)[brow + (roff) + sk[kc]];

#define MM(smb, sn, af, bf)                                                     \
    do {                                                                        \
        __builtin_amdgcn_s_setprio(1);                                          \
        _Pragma("unroll")                                                       \
        for (int kc = 0; kc < 4; ++kc)                                          \
            _Pragma("unroll")                                                   \
            for (int sm = 0; sm < 2; ++sm)                                      \
                acc[(smb) + sm][(sn)] =                                         \
                    __builtin_amdgcn_mfma_f32_32x32x16_bf16(                    \
                        af[sm][kc], bf[kc], acc[(smb) + sm][(sn)], 0, 0, 0);    \
        __builtin_amdgcn_s_setprio(0);                                          \
    } while (0)

#define BAR()   __builtin_amdgcn_s_barrier()
#define SBAR()  __builtin_amdgcn_sched_barrier(0)
#define LGKM0() do { asm volatile("s_waitcnt lgkmcnt(0)" ::: "memory"); SBAR(); } while (0)

    bf16x8 aL[2][4], aH[2][4], bL[4], bH[4];
    const bf16x8* pa0 = &sA[0][0];
    const bf16x8* pb0 = &sB[0][0];
    const bf16x8* pa1 = &sA[1][0];
    const bf16x8* pb1 = &sB[1][0];

    // prologue: tile0 full -> buf0; tile1 B halves -> buf1.B ; keep newest 4
    SH(A0b, aB);  SH(A0b + 16384, aB + (size_t)128 * K);
    SH(B0b, bB);  SH(B0b + 16384, bB + (size_t)128 * K);
    SH(B1b, bB + 64);  SH(B1b + 16384, bB + 64 + (size_t)128 * K);
    asm volatile("s_waitcnt vmcnt(4)" ::: "memory");   // tile0 resident
    BAR();

    #pragma unroll 1
    for (int p = 0; p < 32; ++p) {
        const bool last = (p == 31);
        const __hip_bfloat16* gAu  = aB + (size_t)(2 * p + 1) * 64;
        const __hip_bfloat16* gAt2 = aB + (size_t)(2 * p + 2) * 64;
        const __hip_bfloat16* gBt2 = bB + (size_t)(2 * p + 2) * 64;
        const __hip_bfloat16* gBt3 = bB + (size_t)(2 * p + 3) * 64;

        // ================= K-tile t = 2p (buf0) =================
        // --- P1: reads aL,bL (12); stage buf1.A0<-u ---
        RD_A(aL, pa0, 0); RD_B(bL, pb0, 0);
        SH(A1b, gAu);
        asm volatile("s_waitcnt lgkmcnt(8)" ::: "memory");
        BAR();
        LGKM0();
        MM(0, 0, aL, bL);
        BAR();
        // --- P2: reads bH (4); stage buf1.A1<-u ---
        RD_B(bH, pb0, 256);
        SH(A1b + 16384, gAu + (size_t)128 * K);
        BAR();
        LGKM0();
        MM(0, 1, aL, bH);
        BAR();
        // --- P3: reads aH (8); stage buf0.B0<-t2 ---
        RD_A(aH, pa0, 512);
        if (!last) SH(B0b, gBt2);
        BAR();
        LGKM0();
        MM(2, 0, aH, bL);
        BAR();
        // --- P4: stage buf0.B1<-t2; vmcnt(4) -> buf1 resident ---
        if (!last) {
            SH(B0b + 16384, gBt2 + (size_t)128 * K);
            asm volatile("s_waitcnt vmcnt(4)" ::: "memory");
        } else {
            asm volatile("s_waitcnt vmcnt(0)" ::: "memory");
        }
        BAR();
        SBAR();
        MM(2, 1, aH, bH);
        BAR();

        // ================= K-tile u = 2p+1 (buf1) =================
        // --- P5: reads aL,bL (12); stage buf0.A0<-t2 ---
        RD_A(aL, pa1, 0); RD_B(bL, pb1, 0);
        if (!last) SH(A0b, gAt2);
        asm volatile("s_waitcnt lgkmcnt(8)" ::: "memory");
        BAR();
        LGKM0();
        MM(0, 0, aL, bL);
        BAR();
        // --- P6: reads bH (4); stage buf0.A1<-t2 ---
        RD_B(bH, pb1, 256);
        if (!last) SH(A0b + 16384, gAt2 + (size_t)128 * K);
        BAR();
        LGKM0();
        MM(0, 1, aL, bH);
        BAR();
        // --- P7: reads aH (8); stage buf1.B0<-t3 ---
        RD_A(aH, pa1, 512);
        if (!last) SH(B1b, gBt3);
        BAR();
        LGKM0();
        MM(2, 0, aH, bL);
        BAR();
        // --- P8: stage buf1.B1<-t3; vmcnt(4) -> buf0 (t2) resident ---
        if (!last) {
            SH(B1b + 16384, gBt3 + (size_t)128 * K);
            asm volatile("s_waitcnt vmcnt(4)" ::: "memory");
        }
        BAR();
        SBAR();
        MM(2, 1, aH, bH);
        if (!last) BAR();
    }
#undef SH
#undef RD_A
#undef RD_B
#undef MM
#undef BAR
#undef SBAR
#undef LGKM0

    // epilogue: 32x32 C/D layout col=lane&31, row=(reg&3)+8*(reg>>2)+4*(lane>>5)
    const int crow0 = bm * 256 + wm * 128;
    const int ccol0 = bn * 256 + wn * 64;
    #pragma unroll
    for (int sn = 0; sn < 2; ++sn) {
        int col = ccol0 + sn * 32 + l31;
        float bv = bias[col];
        #pragma unroll
        for (int sm = 0; sm < 4; ++sm) {
            #pragma unroll
            for (int reg = 0; reg < 16; ++reg) {
                int row = crow0 + sm * 32 + (reg & 3) + 8 * (reg >> 2) + 4 * lh;
                C[(size_t)row * N_DIM + col] = acc[sm][sn][reg] + bv;
            }
        }
    }
}

// ---------- fallback (ws too small): fp32 LDS-tiled, correct but slow ----------
__global__ __launch_bounds__(256)
void gemm_fallback(const float* __restrict__ X, const float* __restrict__ W,
                   const float* __restrict__ scale, const float* __restrict__ bias,
                   float* __restrict__ C) {
    int bm = blockIdx.x % (M_DIM / 64);
    int bn = blockIdx.x / (M_DIM / 64);
    __shared__ float sA[64][33];
    __shared__ float sB[64][33];
    int t = threadIdx.x;
    int tx = t & 15, ty = t >> 4;
    float acc[4][4] = {};
    for (int kt = 0; kt < K_DIM / 32; ++kt) {
        float s = scale[(bn >> 1) * (K_DIM / 128) + (kt >> 2)];
        #pragma unroll
        for (int i = 0; i < 8; ++i) {
            int idx = t + i * 256;
            int r = idx >> 5, c = idx & 31;
            sA[r][c] = X[(size_t)(bm * 64 + r) * K_DIM + kt * 32 + c];
            sB[r][c] = W[(size_t)(bn * 64 + r) * K_DIM + kt * 32 + c] * s;
        }
        __syncthreads();
        #pragma unroll
        for (int k = 0; k < 32; ++k) {
            float a[4], b[4];
            #pragma unroll
            for (int i = 0; i < 4; ++i) a[i] = sA[ty * 4 + i][k];
            #pragma unroll
            for (int j = 0; j < 4; ++j) b[j] = sB[tx * 4 + j][k];
            #pragma unroll
            for (int i = 0; i < 4; ++i)
                #pragma unroll
                for (int j = 0; j < 4; ++j) acc[i][j] += a[i] * b[j];
        }
        __syncthreads();
    }
    #pragma unroll
    for (int i = 0; i < 4; ++i)
        #pragma unroll
        for (int j = 0; j < 4; ++j) {
            int row = bm * 64 + ty * 4 + i;
            int col = bn * 64 + tx * 4 + j;
            C[(size_t)row * N_DIM + col] = acc[i][j] + bias[col];
        }
}

extern "C" void kernel_launch(void* const* d_in, const int* in_sizes, int n_in,
                              void* d_out, int out_size, void* d_ws, size_t ws_size,
                              hipStream_t stream) {
    const float* x     = (const float*)d_in[0];   // [2,2048,4096]
    const float* wgt   = (const float*)d_in[1];   // [16384,4096]
    const float* scale = (const float*)d_in[2];   // [128,32]
    const float* bias  = (const float*)d_in[3];   // [16384]
    float* out = (float*)d_out;                   // [2,2048,16384]

    const size_t need = ((size_t)M_DIM * K_DIM + (size_t)N_DIM * K_DIM) * sizeof(__hip_bfloat16);
    if (ws_size >= need) {
        __hip_bfloat16* xbf = (__hip_bfloat16*)d_ws;
        __hip_bfloat16* wbf = xbf + (size_t)M_DIM * K_DIM;
        prep_kernel<<<6144, 256, 0, stream>>>(x, wgt, scale, xbf, wbf);
        gemm_bf16_kernel<<<(M_DIM / 256) * (N_DIM / 256), 512, 0, stream>>>(xbf, wbf, bias, out);
    } else {
        gemm_fallback<<<(M_DIM / 64) * (N_DIM / 64), 256, 0, stream>>>(x, wgt, scale, bias, out);
    }
}